// Round 7
// baseline (230.175 us; speedup 1.0000x reference)
//
#include <hip/hip_runtime.h>
#include <hip/hip_bf16.h>
#include <hip/hip_fp16.h>
#include <math.h>

#define N_GRAPHS 64
#define N_CLASSES 10
#define FIXSCALE 262144.0f  // 2^18 fixed-point scale for packed degree sum (24-bit field)
#define MAXDEG 64           // deg ~ Poisson(16): P(deg>=64) ~ 1e-18/node — safe

typedef __hip_bfloat16 bf16;
typedef int          i32x4 __attribute__((ext_vector_type(4)));
typedef _Float16     f16x8 __attribute__((ext_vector_type(8)));
typedef float        f32x4 __attribute__((ext_vector_type(4)));

// edge record: row (16 high bits) | fp16 sigmoid(P) (16 low bits). Zero record == no-op.
__device__ __forceinline__ unsigned int pack_edge(int r, float s) {
    return ((unsigned int)r << 16) | (unsigned int)__half_as_ushort(__float2half(s));
}

// ---------------- init: zero packed hist + pool buffers (pre[] is gone: sigmoid moved
// into hist_k's matched lanes, computed exactly once per edge as before) ----------------
__global__ void init_k(unsigned int* __restrict__ packed,
                       float* __restrict__ sums, float* __restrict__ cntG, int n) {
    int i = blockIdx.x * 256 + threadIdx.x;
    if (i < n) packed[i] = 0u;
    if (i < N_GRAPHS * 64) sums[i] = 0.0f;
    if (i < N_GRAPHS) cntG[i] = 0.0f;
}

// ---------------- hist + direct ELL scatter, XCD-affine 8-way bucketed ----------------
// Streams ONLY col (3.2MB x 8 passes); row/P are gathered just for the 1/8 matching
// lanes and sigmoid is computed there (once per edge overall — same expf numerics as
// before). Cuts dense VMEM per pass from 12B/edge to 4B/edge; round-3 counters showed
// hist is issue/latency-bound (VALUBusy 4.8%, 21% HBM), so halving VMEM issue is the lever.
__device__ __forceinline__ int bucket_of(int c) {
    int b = (int)(((unsigned int)c * 41u) >> 18);
    return b > 7 ? 7 : b;
}

__device__ __forceinline__ void do_edge(int c, int e, int myb,
                                        const int* __restrict__ row,
                                        const float* __restrict__ P,
                                        unsigned int* __restrict__ packed,
                                        unsigned int* __restrict__ ell) {
    if (bucket_of(c) == myb) {
        float s = 1.0f / (1.0f + expf(-P[e]));
        unsigned int rec = pack_edge(row[e], s);
        unsigned int fix = (unsigned int)(s * FIXSCALE + 0.5f);
        unsigned int old = atomicAdd(&packed[c], (1u << 24) | fix);
        unsigned int rank = old >> 24;
        if (rank < MAXDEG) ell[c * MAXDEG + rank] = rec;
    }
}

__global__ __launch_bounds__(256) void hist_k(const float* __restrict__ P,
                                              const int* __restrict__ row,
                                              const int* __restrict__ col,
                                              unsigned int* __restrict__ packed,
                                              unsigned int* __restrict__ ell, int E) {
    const int myb = blockIdx.x & 7;        // bucket == XCD (1568 blocks: all co-resident)
    const int slice = blockIdx.x >> 3;
    const int E4 = E >> 2;
    const i32x4* col4 = (const i32x4*)col;
#pragma unroll
    for (int k = 0; k < 4; ++k) {
        int i4 = slice * 1024 + k * 256 + (int)threadIdx.x;
        if (i4 < E4) {
            i32x4 c = col4[i4];
            int e = i4 * 4;
            do_edge(c[0], e + 0, myb, row, P, packed, ell);
            do_edge(c[1], e + 1, myb, row, P, packed, ell);
            do_edge(c[2], e + 2, myb, row, P, packed, ell);
            do_edge(c[3], e + 3, myb, row, P, packed, ell);
        }
    }
    if (slice == 0) {  // scalar tail if E % 4 != 0 (E=800000: empty)
        for (int e = E4 * 4 + (int)threadIdx.x; e < E; e += 256)
            do_edge(col[e], e, myb, row, P, packed, ell);
    }
}

// ---------------- dis, xg = bf16(dis*x), and ELL tail zero-pad (to 8-multiples) ------------
__global__ void disxg_k(const unsigned int* __restrict__ packed,
                        const float* __restrict__ x,
                        float* __restrict__ dis, bf16* __restrict__ xg,
                        unsigned int* __restrict__ ell, int n) {
    int i = blockIdx.x * 256 + threadIdx.x;
    if (i < n * 64) {
        int node = i >> 6;
        int lane = i & 63;
        unsigned int pk = packed[node];
        float deg = 1.0f + (float)(pk & 0xFFFFFFu) * (1.0f / FIXSCALE);
        float dv = 1.0f / sqrtf(deg);
        xg[i] = __float2bfloat16(x[i] * dv);
        if (lane == 0) dis[node] = dv;
        int cnt = (int)(pk >> 24);
        if (cnt > MAXDEG) cnt = MAXDEG;
        int pad = ((cnt + 7) & ~7) - cnt;  // 0..7 (agg batches 8-wide now)
        if (lane < pad) ell[node * MAXDEG + cnt + lane] = 0u;
    }
}

// ---------------- fold tail linears + pre-swizzle W1/W2 into MFMA B-fragment order ----------
// Wsw layout: flat index u = ((t*2+k2)*64 + lane)*8 + j holds
//   fp16( W[ k2*32 + (lane>>4)*8 + j ][ t*16 + (lane&15) ] )
__global__ void fold_k(const float* __restrict__ W3, const float* __restrict__ b3,
                       const float* __restrict__ Wl, const float* __restrict__ bl,
                       const float* __restrict__ W1, const float* __restrict__ W2,
                       float* __restrict__ Wc, float* __restrict__ bc,
                       __half* __restrict__ W1h, __half* __restrict__ W2h) {
    int t = blockIdx.x * 256 + threadIdx.x;
    if (t < 64 * N_CLASSES) {
        int k = t / N_CLASSES, c = t % N_CLASSES;
        float acc = 0.0f;
        for (int m = 0; m < 64; ++m) acc += W3[k * 64 + m] * Wl[m * N_CLASSES + c];
        Wc[t] = acc;
    }
    if (t < N_CLASSES) {
        float acc = bl[t];
        for (int m = 0; m < 64; ++m) acc += b3[m] * Wl[m * N_CLASSES + t];
        bc[t] = acc;
    }
    if (t < 8192) {
        int u = t & 4095;
        int j = u & 7, lane = (u >> 3) & 63, k2 = (u >> 9) & 1, tt = u >> 10;
        int srow = k2 * 32 + (lane >> 4) * 8 + j;
        int scol = tt * 16 + (lane & 15);
        const float* W = (t < 4096) ? W1 : W2;
        __half* Wh = (t < 4096) ? W1h : W2h;
        Wh[u] = __float2half(W[srow * 64 + scol]);
    }
}

__device__ __forceinline__ float edge_term(unsigned int v, const bf16* g, int lane) {
    int r = (int)(v >> 16);
    float s = __half2float(__ushort_as_half((unsigned short)(v & 0xFFFFu)));
    return s * __bfloat162float(g[r * 64 + lane]);
}

// ---------------- pure aggregation on the dis-scaled table g = dis*h ----------------
// acc = dis_c * (g[node] + sum_e s_e * g[row_e])   (== reference agg exactly)
// 8-wide batches (tail zero-padded to 8 by disxg_k): Poisson(16) degree means batch-16
// processed ~23 slots/node, batch-8 processes ~20 — 12% fewer gathers+FMAs, still one
// s_load_dwordx8 of the ELL row per iteration.
template <int OUTF>
__global__ __launch_bounds__(256) void agg_k(const bf16* __restrict__ g,
                                             const unsigned int* __restrict__ ell,
                                             const unsigned int* __restrict__ packed,
                                             const float* __restrict__ dis,
                                             float* __restrict__ out,
                                             __half* __restrict__ outH, int n) {
    int tid = threadIdx.x;
    int node = __builtin_amdgcn_readfirstlane(blockIdx.x * 4 + (tid >> 6));
    if (node >= n) return;
    int lane = tid & 63;

    float d = dis[node];
    int cnt = (int)(packed[node] >> 24);
    if (cnt > MAXDEG) cnt = MAXDEG;
    int cnt8 = (cnt + 7) & ~7;  // tail slots zeroed by disxg_k
    float acc = __bfloat162float(g[node * 64 + lane]);  // self loop: dis*h[node]
    const unsigned int* rowp = ell + node * MAXDEG;

    float a[8];
#pragma unroll
    for (int t = 0; t < 8; ++t) a[t] = 0.0f;
    for (int j = 0; j < cnt8; j += 8) {  // uniform: s_load_dwordx8
        unsigned int v[8];
#pragma unroll
        for (int t = 0; t < 8; ++t) v[t] = rowp[j + t];
#pragma unroll
        for (int t = 0; t < 8; ++t) a[t] += edge_term(v[t], g, lane);
    }
#pragma unroll
    for (int off = 4; off >= 1; off >>= 1)
#pragma unroll
        for (int t = 0; t < off; ++t) a[t] += a[t + off];
    acc += a[0];
    acc *= d;  // apply dis_c once

    if (OUTF == 1) outH[(size_t)node * 64 + lane] = __float2half(acc);
    else           out[(size_t)node * 64 + lane] = acc;
}

// ---------------- dense layer GEMM via MFMA: g_next = bf16(dis * relu(A @ W + b)) ----------
__global__ __launch_bounds__(256) void gemm_k(const __half* __restrict__ A,
                                              const __half* __restrict__ Wsw,
                                              const float* __restrict__ b,
                                              const float* __restrict__ dis,
                                              bf16* __restrict__ outg, int n) {
    int tid = threadIdx.x;
    int grp = blockIdx.x * 4 + (tid >> 6);
    int rbase = grp * 16;
    if (rbase >= n) return;
    int l = tid & 63, lr = l & 15, lh = l >> 4;

    const f16x8* Ap = (const f16x8*)(A + (size_t)(rbase + lr) * 64 + lh * 8);
    f16x8 a0 = Ap[0];   // k in [lh*8, lh*8+8)
    f16x8 a1 = Ap[4];   // +32 halves
    const f16x8* Wp = (const f16x8*)Wsw;

    float dv[4];
#pragma unroll
    for (int r = 0; r < 4; ++r) dv[r] = dis[rbase + lh * 4 + r];

#pragma unroll
    for (int t = 0; t < 4; ++t) {
        f32x4 acc = {0.0f, 0.0f, 0.0f, 0.0f};
        acc = __builtin_amdgcn_mfma_f32_16x16x32_f16(a0, Wp[(t * 2 + 0) * 64 + l], acc, 0, 0, 0);
        acc = __builtin_amdgcn_mfma_f32_16x16x32_f16(a1, Wp[(t * 2 + 1) * 64 + l], acc, 0, 0, 0);
        int col = t * 16 + lr;
        float bc_ = b[col];
#pragma unroll
        for (int r = 0; r < 4; ++r) {
            float v = fmaxf(acc[r] + bc_, 0.0f) * dv[r];
            outg[(size_t)(rbase + lh * 4 + r) * 64 + col] = __float2bfloat16(v);
        }
    }
}

// ---------------- pooling phase A: segmented partial sums, flush on graph change ----------------
__global__ __launch_bounds__(256) void poolpart_k(const float* __restrict__ h,
                                                  const int* __restrict__ batch,
                                                  float* __restrict__ sums,
                                                  float* __restrict__ cntG, int n) {
    int wave = threadIdx.x >> 6, lane = threadIdx.x & 63;
    int base = blockIdx.x * 128 + wave * 32;
    if (base >= n) return;
    int end = base + 32; if (end > n) end = n;
    int g = batch[base];
    float acc = 0.0f;
    int run = 0;
    for (int i = base; i < end; ++i) {
        int gi = batch[i];
        if (gi != g) {
            atomicAdd(&sums[g * 64 + lane], acc);
            if (lane == 0) atomicAdd(&cntG[g], (float)run);
            g = gi; acc = 0.0f; run = 0;
        }
        acc += h[i * 64 + lane];
        ++run;
    }
    atomicAdd(&sums[g * 64 + lane], acc);
    if (lane == 0) atomicAdd(&cntG[g], (float)run);
}

// ---------------- pooling phase B: mean + folded classifier (Wc, bc) ----------------
__global__ void classify_k(const float* __restrict__ sums, const float* __restrict__ cntG,
                           const float* __restrict__ Wc, const float* __restrict__ bc,
                           float* __restrict__ out) {
    __shared__ float pooled[64];
    int g = blockIdx.x;
    int t = threadIdx.x;  // 64
    float inv = 1.0f / fmaxf(cntG[g], 1.0f);
    pooled[t] = sums[g * 64 + t] * inv;
    __syncthreads();
    if (t < N_CLASSES) {
        float acc = bc[t];
        for (int k = 0; k < 64; ++k) acc += pooled[k] * Wc[k * N_CLASSES + t];
        out[g * N_CLASSES + t] = acc;
    }
}

extern "C" void kernel_launch(void* const* d_in, const int* in_sizes, int n_in,
                              void* d_out, int out_size, void* d_ws, size_t ws_size,
                              hipStream_t stream) {
    const float* x     = (const float*)d_in[0];
    const int*   eidx  = (const int*)d_in[1];
    const int*   batch = (const int*)d_in[2];
    const float* P     = (const float*)d_in[3];
    const float* W1 = (const float*)d_in[4];
    const float* b1 = (const float*)d_in[5];
    const float* W2 = (const float*)d_in[6];
    const float* b2 = (const float*)d_in[7];
    const float* W3 = (const float*)d_in[8];
    const float* b3 = (const float*)d_in[9];
    const float* Wl = (const float*)d_in[10];
    const float* bl = (const float*)d_in[11];
    float* out = (float*)d_out;

    const int N = in_sizes[2];      // 50000
    const int E = in_sizes[3];      // 800000
    const int* row = eidx;
    const int* col = eidx + E;

    // workspace layout — large 16B-multiple buffers first (d_ws >=256B aligned)
    char* p = (char*)d_ws;
    unsigned int* ell = (unsigned int*)p; p += (size_t)N * MAXDEG * 4;  // 12.8 MB
    float* bufF     = (float*)p; p += (size_t)N * 64 * 4;   // f32 h3 for pooling
    bf16*  xg       = (bf16*)p;  p += (size_t)N * 64 * 2;   // g0 = dis*x; reused as g2
    bf16*  gA       = (bf16*)p;  p += (size_t)N * 64 * 2;   // g1
    __half* aH      = (__half*)p; p += (size_t)N * 64 * 2;  // fp16 agg output (MFMA A)
    unsigned int* packed = (unsigned int*)p; p += (size_t)N * 4;
    float* dis      = (float*)p; p += (size_t)N * 4;
    float* sums     = (float*)p; p += (size_t)N_GRAPHS * 64 * 4;
    float* cntG     = (float*)p; p += (size_t)N_GRAPHS * 4;
    float* Wc       = (float*)p; p += (size_t)64 * N_CLASSES * 4;
    __half* W1h     = (__half*)p; p += 4096 * 2;            // swizzled fp16 W1 frags
    __half* W2h     = (__half*)p; p += 4096 * 2;            // swizzled fp16 W2 frags
    float* bc       = (float*)p; p += (size_t)N_CLASSES * 4;
    bf16*  gB       = xg;  // g2 aliases xg (g0 dead after layer-1 agg)

    dim3 blk(256);
    int nodeG = (N + 255) / 256;           // 196
    int bigG  = (N * 64 + 255) / 256;      // 12500

    init_k<<<nodeG, blk, 0, stream>>>(packed, sums, cntG, N);
    int nslice = ((E >> 2) + 1023) / 1024;         // 196
    hist_k<<<nslice * 8, blk, 0, stream>>>(P, row, col, packed, ell, E);  // 1568: all resident
    disxg_k<<<bigG, blk, 0, stream>>>(packed, x, dis, xg, ell, N);
    fold_k<<<32, blk, 0, stream>>>(W3, b3, Wl, bl, W1, W2, Wc, bc, W1h, W2h);

    int aggG  = (N + 3) / 4;        // 12500: 1 node/wave
    int gemmG = (N / 16 + 3) / 4;   // 782: 16 rows/wave

    // Layer 1: A = agg(g0);  g1 = dis*relu(A @ W1 + b1)   (MFMA)
    agg_k<1><<<aggG, blk, 0, stream>>>(xg, ell, packed, dis, nullptr, aH, N);
    gemm_k<<<gemmG, blk, 0, stream>>>(aH, W1h, b1, dis, gA, N);
    // Layer 2: A = agg(g1);  g2 = dis*relu(A @ W2 + b2)
    agg_k<1><<<aggG, blk, 0, stream>>>(gA, ell, packed, dis, nullptr, aH, N);
    gemm_k<<<gemmG, blk, 0, stream>>>(aH, W2h, b2, dis, gB, N);
    // Layer 3 (pure agg; W3/b3 folded into classifier), f32 out for pooling
    agg_k<0><<<aggG, blk, 0, stream>>>(gB, ell, packed, dis, bufF, nullptr, N);

    // pool + folded classifier
    int poolG = (N + 127) / 128;
    poolpart_k<<<poolG, blk, 0, stream>>>(bufF, batch, sums, cntG, N);
    classify_k<<<N_GRAPHS, dim3(64), 0, stream>>>(sums, cntG, Wc, bc, out);
}